// Round 1
// baseline (833.278 us; speedup 1.0000x reference)
//
#include <hip/hip_runtime.h>
#include <hip/hip_bf16.h>
#include <stdint.h>
#include <cmath>

typedef __bf16 bf16x8 __attribute__((ext_vector_type(8)));
typedef float f32x4 __attribute__((ext_vector_type(4)));

#define NB 8
#define NS 2048
#define ND 1024
#define NO 512

__device__ __forceinline__ unsigned short f2bf(float f) {
  union { float f; uint32_t u; } c;
  c.f = f;
  uint32_t u = c.u;
  uint32_t r = (u + 0x7fffu + ((u >> 16) & 1u)) >> 16;
  return (unsigned short)r;
}

__device__ __forceinline__ void glds16(const void* g, void* l) {
  __builtin_amdgcn_global_load_lds(
      (const __attribute__((address_space(1))) unsigned int*)g,
      (__attribute__((address_space(3))) unsigned int*)l, 16, 0, 0);
}

// ---------------- cast x (fp32 -> bf16), 8 elems/thread ----------------
__global__ void cast_x_kernel(const float* __restrict__ in,
                              unsigned short* __restrict__ out, int n8) {
  int i = blockIdx.x * blockDim.x + threadIdx.x;
  if (i >= n8) return;
  const float4* p = reinterpret_cast<const float4*>(in) + 2 * (size_t)i;
  float4 a = p[0], b = p[1];
  union { unsigned short us[8]; int4 v; } r;
  r.us[0] = f2bf(a.x); r.us[1] = f2bf(a.y); r.us[2] = f2bf(a.z); r.us[3] = f2bf(a.w);
  r.us[4] = f2bf(b.x); r.us[5] = f2bf(b.y); r.us[6] = f2bf(b.z); r.us[7] = f2bf(b.w);
  reinterpret_cast<int4*>(out)[i] = r.v;
}

// ------------- transpose+cast weights: in[R][C] f32 -> out[C][R] bf16 -------------
__global__ void transpose_cast_kernel(const float* __restrict__ in,
                                      unsigned short* __restrict__ out,
                                      int R, int C) {
  __shared__ unsigned short t[32][33];
  int bx = blockIdx.x;  // C/32
  int by = blockIdx.y;  // R/32
  int x = threadIdx.x & 31, y = threadIdx.x >> 5;  // y: 0..7
#pragma unroll
  for (int j = 0; j < 4; j++) {
    int r = by * 32 + y + j * 8;
    int c = bx * 32 + x;
    t[y + j * 8][x] = f2bf(in[(size_t)r * C + c]);
  }
  __syncthreads();
#pragma unroll
  for (int j = 0; j < 4; j++) {
    int c = bx * 32 + y + j * 8;
    int r = by * 32 + x;
    out[(size_t)c * R + r] = t[x][y + j * 8];
  }
}

// ------------- transpose V: [B][S][O] bf16 -> [B][O][S] bf16 -------------
__global__ void transpose_v_kernel(const unsigned short* __restrict__ in,
                                   unsigned short* __restrict__ out) {
  __shared__ unsigned short t[32][33];
  int b = blockIdx.z;
  int bo = blockIdx.x;  // O/32
  int bs = blockIdx.y;  // S/32
  const unsigned short* ib = in + (size_t)b * NS * NO;
  unsigned short* ob = out + (size_t)b * NO * NS;
  int x = threadIdx.x & 31, y = threadIdx.x >> 5;
#pragma unroll
  for (int j = 0; j < 4; j++)
    t[y + j * 8][x] = ib[(size_t)(bs * 32 + y + j * 8) * NO + bo * 32 + x];
  __syncthreads();
#pragma unroll
  for (int j = 0; j < 4; j++)
    ob[(size_t)(bo * 32 + y + j * 8) * NS + bs * 32 + x] = t[x][y + j * 8];
}

// ------------- GEMM: C[M][N] = A[M][K] @ Bt[N][K]^T + bias, bf16 in/out -------------
// 128x128 tile, BK=32, 4 waves, mfma 16x16x32 bf16 (m97 structure)
__global__ __launch_bounds__(256, 2) void gemm_bias_kernel(
    const unsigned short* __restrict__ A, const unsigned short* __restrict__ Bt,
    const float* __restrict__ bias, unsigned short* __restrict__ C,
    int M, int N, int K) {
  __shared__ unsigned short lA[128 * 32];
  __shared__ unsigned short lB[128 * 32];
  const int tid = threadIdx.x;
  const int w = tid >> 6, l = tid & 63;
  const int m0 = blockIdx.x * 128, n0 = blockIdx.y * 128;
  const int wr = w >> 1, wc = w & 1;
  const int lr16 = l & 15, lg = l >> 4;
  f32x4 acc[4][4];
#pragma unroll
  for (int i = 0; i < 4; i++)
#pragma unroll
    for (int j = 0; j < 4; j++) acc[i][j] = (f32x4){0.f, 0.f, 0.f, 0.f};
  const int srow = w * 32 + (l >> 2);  // staging row (+j*16)
  const int sk = (l & 3) * 8;          // staging k-elems
  for (int k0 = 0; k0 < K; k0 += 32) {
#pragma unroll
    for (int j = 0; j < 2; j++) {
      glds16(&A[(size_t)(m0 + srow + j * 16) * K + k0 + sk], &lA[w * 1024 + j * 512]);
      glds16(&Bt[(size_t)(n0 + srow + j * 16) * K + k0 + sk], &lB[w * 1024 + j * 512]);
    }
    __syncthreads();
    bf16x8 af[4], bfr[4];
#pragma unroll
    for (int mi = 0; mi < 4; mi++)
      af[mi] = *reinterpret_cast<const bf16x8*>(&lA[(wr * 64 + mi * 16 + lr16) * 32 + lg * 8]);
#pragma unroll
    for (int ni = 0; ni < 4; ni++)
      bfr[ni] = *reinterpret_cast<const bf16x8*>(&lB[(wc * 64 + ni * 16 + lr16) * 32 + lg * 8]);
#pragma unroll
    for (int mi = 0; mi < 4; mi++)
#pragma unroll
      for (int ni = 0; ni < 4; ni++)
        acc[mi][ni] = __builtin_amdgcn_mfma_f32_16x16x32_bf16(af[mi], bfr[ni], acc[mi][ni], 0, 0, 0);
    __syncthreads();
  }
#pragma unroll
  for (int ni = 0; ni < 4; ni++) {
    int col = n0 + wc * 64 + ni * 16 + lr16;
    float bv = bias[col];
#pragma unroll
    for (int mi = 0; mi < 4; mi++) {
#pragma unroll
      for (int i = 0; i < 4; i++) {
        int row = m0 + wr * 64 + mi * 16 + lg * 4 + i;
        C[(size_t)row * N + col] = f2bf(acc[mi][ni][i] + bv);
      }
    }
  }
}

// ------------- Flash attention: Q[B*S][D], K[B*S][D], Vt[B][O][S] -> Out[B][S][O] -------------
// block = (batch b, 64-row q tile qi); 4 waves, wave w owns S-rows [w*16, w*16+16)
__global__ __launch_bounds__(256, 2) void flash_kernel(
    const unsigned short* __restrict__ Q, const unsigned short* __restrict__ K,
    const unsigned short* __restrict__ Vt, float* __restrict__ Out) {
  __shared__ unsigned short lQ[64 * 128];  // 16KB (aliased by lV in PV phase)
  __shared__ unsigned short lK[64 * 128];  // 16KB
  __shared__ unsigned short lP[64 * 64];   // 8KB
  unsigned short* lV = lQ;
  const int bid = blockIdx.x;
  const int b = bid & 7, qi = bid >> 3;  // b -> XCD (round-robin) for K/V L2 locality
  const int tid = threadIdx.x, w = tid >> 6, l = tid & 63;
  const unsigned short* Qb = Q + (size_t)b * NS * ND;
  const unsigned short* Kb = K + (size_t)b * NS * ND;
  const unsigned short* Vb = Vt + (size_t)b * NO * NS;
  float* Ob = Out + (size_t)b * NS * NO;
  const int q0 = qi * 64;
  const int lr16 = l & 15, lg = l >> 4;
  f32x4 acc_o[32];
#pragma unroll
  for (int f = 0; f < 32; f++) acc_o[f] = (f32x4){0.f, 0.f, 0.f, 0.f};
  float m_s[4], l_s[4];
#pragma unroll
  for (int i = 0; i < 4; i++) { m_s[i] = -INFINITY; l_s[i] = 0.f; }
  const float sc = 0.03125f * 1.4426950408889634f;  // 1/sqrt(1024) * log2(e)

  for (int ki = 0; ki <= qi; ++ki) {
    const int k0 = ki * 64;
    f32x4 accs[4];
#pragma unroll
    for (int f = 0; f < 4; f++) accs[f] = (f32x4){0.f, 0.f, 0.f, 0.f};
    // ---- phase A: S = Q @ K^T over d-chunks of 128 ----
    for (int dc = 0; dc < ND; dc += 128) {
#pragma unroll
      for (int j = 0; j < 4; j++) {
        glds16(&Qb[(size_t)(q0 + w * 16 + j * 4 + lg) * ND + dc + lr16 * 8], &lQ[w * 2048 + j * 512]);
        glds16(&Kb[(size_t)(k0 + w * 16 + j * 4 + lg) * ND + dc + lr16 * 8], &lK[w * 2048 + j * 512]);
      }
      __syncthreads();
#pragma unroll
      for (int ks = 0; ks < 4; ks++) {
        bf16x8 a = *reinterpret_cast<const bf16x8*>(&lQ[(w * 16 + lr16) * 128 + ks * 32 + lg * 8]);
#pragma unroll
        for (int fn = 0; fn < 4; fn++) {
          bf16x8 bb = *reinterpret_cast<const bf16x8*>(&lK[(fn * 16 + lr16) * 128 + ks * 32 + lg * 8]);
          accs[fn] = __builtin_amdgcn_mfma_f32_16x16x32_bf16(a, bb, accs[fn], 0, 0, 0);
        }
      }
      __syncthreads();
    }
    // ---- phase B: online softmax (in-register, wave-parallel) ----
    const bool diag = (ki == qi);
    float alpha[4];
#pragma unroll
    for (int i = 0; i < 4; i++) {
      float v0 = accs[0][i] * sc, v1 = accs[1][i] * sc;
      float v2 = accs[2][i] * sc, v3 = accs[3][i] * sc;
      if (diag) {
        int qr = w * 16 + lg * 4 + i;  // local row; k0 == q0 so compare local
        if (lr16 > qr) v0 = -INFINITY;
        if (16 + lr16 > qr) v1 = -INFINITY;
        if (32 + lr16 > qr) v2 = -INFINITY;
        if (48 + lr16 > qr) v3 = -INFINITY;
      }
      float pm = fmaxf(fmaxf(v0, v1), fmaxf(v2, v3));
      pm = fmaxf(pm, __shfl_xor(pm, 1));
      pm = fmaxf(pm, __shfl_xor(pm, 2));
      pm = fmaxf(pm, __shfl_xor(pm, 4));
      pm = fmaxf(pm, __shfl_xor(pm, 8));
      float mn = fmaxf(m_s[i], pm);
      float al = exp2f(m_s[i] - mn);
      float p0 = exp2f(v0 - mn), p1 = exp2f(v1 - mn);
      float p2 = exp2f(v2 - mn), p3 = exp2f(v3 - mn);
      float rs = (p0 + p1) + (p2 + p3);
      rs += __shfl_xor(rs, 1);
      rs += __shfl_xor(rs, 2);
      rs += __shfl_xor(rs, 4);
      rs += __shfl_xor(rs, 8);
      l_s[i] = l_s[i] * al + rs;
      m_s[i] = mn;
      alpha[i] = al;
      accs[0][i] = p0; accs[1][i] = p1; accs[2][i] = p2; accs[3][i] = p3;
    }
#pragma unroll
    for (int f = 0; f < 32; f++)
#pragma unroll
      for (int i = 0; i < 4; i++) acc_o[f][i] *= alpha[i];
    // ---- phase C: P -> LDS (bf16) ----
#pragma unroll
    for (int fn = 0; fn < 4; fn++)
#pragma unroll
      for (int i = 0; i < 4; i++)
        lP[(w * 16 + lg * 4 + i) * 64 + fn * 16 + lr16] = f2bf(accs[fn][i]);
    __syncthreads();
    // ---- phase D: O += P @ V (Vt chunks of 128 cols) ----
    for (int nc = 0; nc < 4; nc++) {
#pragma unroll
      for (int j = 0; j < 4; j++)
        glds16(&Vb[(size_t)(nc * 128 + w * 32 + j * 8 + (l >> 3)) * NS + k0 + (l & 7) * 8],
               &lV[w * 2048 + j * 512]);
      __syncthreads();
      bf16x8 a0 = *reinterpret_cast<const bf16x8*>(&lP[(w * 16 + lr16) * 64 + lg * 8]);
      bf16x8 a1 = *reinterpret_cast<const bf16x8*>(&lP[(w * 16 + lr16) * 64 + 32 + lg * 8]);
#pragma unroll
      for (int fc = 0; fc < 8; fc++) {
        bf16x8 b0 = *reinterpret_cast<const bf16x8*>(&lV[(fc * 16 + lr16) * 64 + lg * 8]);
        bf16x8 b1 = *reinterpret_cast<const bf16x8*>(&lV[(fc * 16 + lr16) * 64 + 32 + lg * 8]);
        int f = nc * 8 + fc;
        acc_o[f] = __builtin_amdgcn_mfma_f32_16x16x32_bf16(a0, b0, acc_o[f], 0, 0, 0);
        acc_o[f] = __builtin_amdgcn_mfma_f32_16x16x32_bf16(a1, b1, acc_o[f], 0, 0, 0);
      }
      __syncthreads();
    }
  }
  // ---- epilogue: normalize and store fp32 ----
  float inv[4];
#pragma unroll
  for (int i = 0; i < 4; i++) inv[i] = 1.0f / l_s[i];
#pragma unroll
  for (int nc = 0; nc < 4; nc++)
#pragma unroll
    for (int fc = 0; fc < 8; fc++)
#pragma unroll
      for (int i = 0; i < 4; i++) {
        int row = q0 + w * 16 + lg * 4 + i;
        int col = nc * 128 + fc * 16 + lr16;
        Ob[(size_t)row * NO + col] = acc_o[nc * 8 + fc][i] * inv[i];
      }
}

extern "C" void kernel_launch(void* const* d_in, const int* in_sizes, int n_in,
                              void* d_out, int out_size, void* d_ws, size_t ws_size,
                              hipStream_t stream) {
  const float* x = (const float*)d_in[0];
  const float* Wq = (const float*)d_in[1];
  const float* bq = (const float*)d_in[2];
  const float* Wk = (const float*)d_in[3];
  const float* bk = (const float*)d_in[4];
  const float* Wv = (const float*)d_in[5];
  const float* bv = (const float*)d_in[6];
  float* out = (float*)d_out;
  char* ws = (char*)d_ws;

  // workspace layout (bytes)
  unsigned short* xb  = (unsigned short*)(ws + 0);          // 33,554,432
  unsigned short* wqt = (unsigned short*)(ws + 33554432);   //  2,097,152
  unsigned short* wkt = (unsigned short*)(ws + 35651584);   //  2,097,152
  unsigned short* wvt = (unsigned short*)(ws + 37748736);   //  1,048,576
  unsigned short* Qb  = (unsigned short*)(ws + 38797312);   // 33,554,432
  unsigned short* Kb  = (unsigned short*)(ws + 72351744);   // 33,554,432
  unsigned short* Vb  = (unsigned short*)(ws + 105906176);  // 16,777,216
  unsigned short* Vtb = (unsigned short*)(ws + 122683392);  // 16,777,216  (end ~133MB)

  // 1) casts
  cast_x_kernel<<<8192, 256, 0, stream>>>(x, xb, (NB * NS * ND) / 8);
  transpose_cast_kernel<<<dim3(32, 32), 256, 0, stream>>>(Wq, wqt, ND, ND);
  transpose_cast_kernel<<<dim3(32, 32), 256, 0, stream>>>(Wk, wkt, ND, ND);
  transpose_cast_kernel<<<dim3(16, 32), 256, 0, stream>>>(Wv, wvt, ND, NO);
  // 2) projections (M=16384)
  gemm_bias_kernel<<<dim3(128, 8), 256, 0, stream>>>(xb, wqt, bq, Qb, NB * NS, ND, ND);
  gemm_bias_kernel<<<dim3(128, 8), 256, 0, stream>>>(xb, wkt, bk, Kb, NB * NS, ND, ND);
  gemm_bias_kernel<<<dim3(128, 4), 256, 0, stream>>>(xb, wvt, bv, Vb, NB * NS, NO, ND);
  // 3) V transpose -> [B][O][S]
  transpose_v_kernel<<<dim3(16, 64, 8), 256, 0, stream>>>(Vb, Vtb);
  // 4) flash attention
  flash_kernel<<<256, 256, 0, stream>>>(Qb, Kb, Vtb, out);
}

// Round 2
// 488.351 us; speedup vs baseline: 1.7063x; 1.7063x over previous
//
#include <hip/hip_runtime.h>
#include <hip/hip_bf16.h>
#include <stdint.h>
#include <cmath>

typedef __bf16 bf16x8 __attribute__((ext_vector_type(8)));
typedef float f32x4 __attribute__((ext_vector_type(4)));

#define NB 8
#define NS 2048
#define ND 1024
#define NO 512

__device__ __forceinline__ unsigned short f2bf(float f) {
  union { float f; uint32_t u; } c;
  c.f = f;
  uint32_t u = c.u;
  uint32_t r = (u + 0x7fffu + ((u >> 16) & 1u)) >> 16;
  return (unsigned short)r;
}

__device__ __forceinline__ void glds16(const void* g, void* l) {
  __builtin_amdgcn_global_load_lds(
      (const __attribute__((address_space(1))) unsigned int*)g,
      (__attribute__((address_space(3))) unsigned int*)l, 16, 0, 0);
}

// ---------------- cast x (fp32 -> bf16), 8 elems/thread ----------------
__global__ void cast_x_kernel(const float* __restrict__ in,
                              unsigned short* __restrict__ out, int n8) {
  int i = blockIdx.x * blockDim.x + threadIdx.x;
  if (i >= n8) return;
  const float4* p = reinterpret_cast<const float4*>(in) + 2 * (size_t)i;
  float4 a = p[0], b = p[1];
  union { unsigned short us[8]; int4 v; } r;
  r.us[0] = f2bf(a.x); r.us[1] = f2bf(a.y); r.us[2] = f2bf(a.z); r.us[3] = f2bf(a.w);
  r.us[4] = f2bf(b.x); r.us[5] = f2bf(b.y); r.us[6] = f2bf(b.z); r.us[7] = f2bf(b.w);
  reinterpret_cast<int4*>(out)[i] = r.v;
}

// ------------- transpose+cast weights: in[R][C] f32 -> out[C][R] bf16 -------------
__global__ void transpose_cast_kernel(const float* __restrict__ in,
                                      unsigned short* __restrict__ out,
                                      int R, int C) {
  __shared__ unsigned short t[32][33];
  int bx = blockIdx.x;  // C/32
  int by = blockIdx.y;  // R/32
  int x = threadIdx.x & 31, y = threadIdx.x >> 5;  // y: 0..7
#pragma unroll
  for (int j = 0; j < 4; j++) {
    int r = by * 32 + y + j * 8;
    int c = bx * 32 + x;
    t[y + j * 8][x] = f2bf(in[(size_t)r * C + c]);
  }
  __syncthreads();
#pragma unroll
  for (int j = 0; j < 4; j++) {
    int c = bx * 32 + y + j * 8;
    int r = by * 32 + x;
    out[(size_t)c * R + r] = t[x][y + j * 8];
  }
}

// ------------- transpose V: [B][S][O] bf16 -> [B][O][S] bf16 -------------
__global__ void transpose_v_kernel(const unsigned short* __restrict__ in,
                                   unsigned short* __restrict__ out) {
  __shared__ unsigned short t[32][33];
  int b = blockIdx.z;
  int bo = blockIdx.x;  // O/32
  int bs = blockIdx.y;  // S/32
  const unsigned short* ib = in + (size_t)b * NS * NO;
  unsigned short* ob = out + (size_t)b * NO * NS;
  int x = threadIdx.x & 31, y = threadIdx.x >> 5;
#pragma unroll
  for (int j = 0; j < 4; j++)
    t[y + j * 8][x] = ib[(size_t)(bs * 32 + y + j * 8) * NO + bo * 32 + x];
  __syncthreads();
#pragma unroll
  for (int j = 0; j < 4; j++)
    ob[(size_t)(bo * 32 + y + j * 8) * NS + bs * 32 + x] = t[x][y + j * 8];
}

// ------------- GEMM: C[M][N] = A[M][K] @ Bt[N][K]^T + bias, bf16 in/out -------------
__global__ __launch_bounds__(256, 2) void gemm_bias_kernel(
    const unsigned short* __restrict__ A, const unsigned short* __restrict__ Bt,
    const float* __restrict__ bias, unsigned short* __restrict__ C,
    int M, int N, int K) {
  __shared__ unsigned short lA[128 * 32];
  __shared__ unsigned short lB[128 * 32];
  const int tid = threadIdx.x;
  const int w = tid >> 6, l = tid & 63;
  const int m0 = blockIdx.x * 128, n0 = blockIdx.y * 128;
  const int wr = w >> 1, wc = w & 1;
  const int lr16 = l & 15, lg = l >> 4;
  f32x4 acc[4][4];
#pragma unroll
  for (int i = 0; i < 4; i++)
#pragma unroll
    for (int j = 0; j < 4; j++) acc[i][j] = (f32x4){0.f, 0.f, 0.f, 0.f};
  const int srow = w * 32 + (l >> 2);
  const int sk = (l & 3) * 8;
  for (int k0 = 0; k0 < K; k0 += 32) {
#pragma unroll
    for (int j = 0; j < 2; j++) {
      glds16(&A[(size_t)(m0 + srow + j * 16) * K + k0 + sk], &lA[w * 1024 + j * 512]);
      glds16(&Bt[(size_t)(n0 + srow + j * 16) * K + k0 + sk], &lB[w * 1024 + j * 512]);
    }
    __syncthreads();
    bf16x8 af[4], bfr[4];
#pragma unroll
    for (int mi = 0; mi < 4; mi++)
      af[mi] = *reinterpret_cast<const bf16x8*>(&lA[(wr * 64 + mi * 16 + lr16) * 32 + lg * 8]);
#pragma unroll
    for (int ni = 0; ni < 4; ni++)
      bfr[ni] = *reinterpret_cast<const bf16x8*>(&lB[(wc * 64 + ni * 16 + lr16) * 32 + lg * 8]);
#pragma unroll
    for (int mi = 0; mi < 4; mi++)
#pragma unroll
      for (int ni = 0; ni < 4; ni++)
        acc[mi][ni] = __builtin_amdgcn_mfma_f32_16x16x32_bf16(af[mi], bfr[ni], acc[mi][ni], 0, 0, 0);
    __syncthreads();
  }
#pragma unroll
  for (int ni = 0; ni < 4; ni++) {
    int col = n0 + wc * 64 + ni * 16 + lr16;
    float bv = bias[col];
#pragma unroll
    for (int mi = 0; mi < 4; mi++) {
#pragma unroll
      for (int i = 0; i < 4; i++) {
        int row = m0 + wr * 64 + mi * 16 + lg * 4 + i;
        C[(size_t)row * N + col] = f2bf(acc[mi][ni][i] + bv);
      }
    }
  }
}

// ------------- Flash attention, pipelined units + swizzled LDS + Q-in-regs -------------
// block = (batch b, 64-row q tile qi); 4 waves, wave w owns q-rows [w*16, w*16+16)
// per k-tile: 12 units of 16KB (8 K-units of [64 kv][128 d], 4 V-units of [128 O][64 kv]);
// 3 LDS buffers, counted vmcnt(4) + raw s_barrier (one unit always in flight).
// LDS swizzle: physical 16B-granule p = logical g ^ (row & 7); global_load_lds keeps a
// linear dest, so the SOURCE column is inverse-swizzled (rule #21: both-sides-or-neither).
__global__ __launch_bounds__(256, 1) void flash_kernel(
    const unsigned short* __restrict__ Q, const unsigned short* __restrict__ K,
    const unsigned short* __restrict__ Vt, float* __restrict__ Out) {
  __shared__ unsigned short ubuf[3 * 8192];  // 3 x 16KB pipeline buffers
  __shared__ unsigned short lP[64 * 64];     // 8KB, swizzled
  const int bid = blockIdx.x;
  const int b = bid & 7, qi = bid >> 3;  // b -> XCD for K/V L2 locality
  const int tid = threadIdx.x, w = tid >> 6, l = tid & 63;
  const unsigned short* Qb = Q + (size_t)b * NS * ND;
  const unsigned short* Kb = K + (size_t)b * NS * ND;
  const unsigned short* Vb = Vt + (size_t)b * NO * NS;
  float* Ob = Out + (size_t)b * NS * NO;
  const int q0 = qi * 64;
  const int lr16 = l & 15, lg = l >> 4;

  // ---- Q tile into registers: lane holds row (w*16+lr16), d-slice (c*32 + lg*8) ----
  bf16x8 qreg[32];
  {
    const unsigned short* qrow = &Qb[(size_t)(q0 + w * 16 + lr16) * ND + lg * 8];
#pragma unroll
    for (int c = 0; c < 32; c++)
      qreg[c] = *reinterpret_cast<const bf16x8*>(qrow + c * 32);
  }

  f32x4 acc_o[32];
#pragma unroll
  for (int f = 0; f < 32; f++) acc_o[f] = (f32x4){0.f, 0.f, 0.f, 0.f};
  float m_s[4], l_s[4];
#pragma unroll
  for (int i = 0; i < 4; i++) { m_s[i] = -INFINITY; l_s[i] = 0.f; }
  const float sc = 0.03125f * 1.4426950408889634f;  // 1/sqrt(1024) * log2(e)

  const int nkt = qi + 1;
  const int total = 12 * nkt;

  // stage global unit g into buffer g%3 (4 x glds16 per thread = 16KB per unit)
  auto stage = [&](int g) {
    int ki = g / 12, u = g - ki * 12;
    int k0 = ki * 64;
    unsigned short* dst = &ubuf[(g % 3) * 8192];
    if (u < 8) {  // K unit u: [64 kv][128 d], d-range u*128
#pragma unroll
      for (int j = 0; j < 4; j++) {
        int row = j * 16 + w * 4 + (l >> 4);
        int gl = (l & 15) ^ (row & 7);  // inverse-swizzled source granule
        glds16(&Kb[(size_t)(k0 + row) * ND + u * 128 + gl * 8],
               dst + j * 2048 + w * 512);
      }
    } else {  // V unit nc: [128 O][64 kv], O-range nc*128
      int nc = u - 8;
#pragma unroll
      for (int j = 0; j < 4; j++) {
        int row = j * 32 + w * 8 + (l >> 3);
        int gl = (l & 7) ^ (row & 7);
        glds16(&Vb[(size_t)(nc * 128 + row) * NS + k0 + gl * 8],
               dst + j * 2048 + w * 512);
      }
    }
  };

  stage(0);
  if (total > 1) stage(1);

  bf16x8 pa0 = {}, pa1 = {};
  for (int ki = 0; ki < nkt; ++ki) {
    const int k0 = ki * 64;
    const int gbase = ki * 12;
    f32x4 accs[4];
#pragma unroll
    for (int f = 0; f < 4; f++) accs[f] = (f32x4){0.f, 0.f, 0.f, 0.f};

#pragma unroll
    for (int u = 0; u < 12; ++u) {
      const int g = gbase + u;
      const bool isLast = (ki == nkt - 1) && (u == 11);
      if (!isLast)
        asm volatile("s_waitcnt vmcnt(4) lgkmcnt(0)\ns_barrier" ::: "memory");
      else
        asm volatile("s_waitcnt vmcnt(0) lgkmcnt(0)\ns_barrier" ::: "memory");
      if ((ki < nkt - 1) || (u < 10)) stage(g + 2);
      const unsigned short* bp = &ubuf[(g % 3) * 8192];

      if (u < 8) {
        // ---- QK^T unit: S += Q[d-slice] * K[d-slice]^T ----
#pragma unroll
        for (int ks = 0; ks < 4; ks++) {
          bf16x8 a = qreg[u * 4 + ks];
#pragma unroll
          for (int fn = 0; fn < 4; fn++) {
            int row = fn * 16 + lr16;
            int p = (ks * 4 + lg) ^ (row & 7);
            bf16x8 bb = *reinterpret_cast<const bf16x8*>(&bp[row * 128 + p * 8]);
            accs[fn] = __builtin_amdgcn_mfma_f32_16x16x32_bf16(a, bb, accs[fn], 0, 0, 0);
          }
        }
        if (u == 7) {
          // ---- online softmax (wave-parallel, in-register) ----
          const bool diag = (ki == qi);
          float alpha[4];
#pragma unroll
          for (int i = 0; i < 4; i++) {
            float v0 = accs[0][i] * sc, v1 = accs[1][i] * sc;
            float v2 = accs[2][i] * sc, v3 = accs[3][i] * sc;
            if (diag) {
              int qr = w * 16 + lg * 4 + i;
              if (lr16 > qr) v0 = -INFINITY;
              if (16 + lr16 > qr) v1 = -INFINITY;
              if (32 + lr16 > qr) v2 = -INFINITY;
              if (48 + lr16 > qr) v3 = -INFINITY;
            }
            float pm = fmaxf(fmaxf(v0, v1), fmaxf(v2, v3));
            pm = fmaxf(pm, __shfl_xor(pm, 1));
            pm = fmaxf(pm, __shfl_xor(pm, 2));
            pm = fmaxf(pm, __shfl_xor(pm, 4));
            pm = fmaxf(pm, __shfl_xor(pm, 8));
            float mn = fmaxf(m_s[i], pm);
            float al = exp2f(m_s[i] - mn);
            float p0 = exp2f(v0 - mn), p1 = exp2f(v1 - mn);
            float p2 = exp2f(v2 - mn), p3 = exp2f(v3 - mn);
            float rs = (p0 + p1) + (p2 + p3);
            rs += __shfl_xor(rs, 1);
            rs += __shfl_xor(rs, 2);
            rs += __shfl_xor(rs, 4);
            rs += __shfl_xor(rs, 8);
            l_s[i] = l_s[i] * al + rs;
            m_s[i] = mn;
            alpha[i] = al;
            accs[0][i] = p0; accs[1][i] = p1; accs[2][i] = p2; accs[3][i] = p3;
          }
#pragma unroll
          for (int f = 0; f < 32; f++)
#pragma unroll
            for (int i = 0; i < 4; i++) acc_o[f][i] *= alpha[i];
          // ---- P -> LDS (bf16, swizzled) ----
#pragma unroll
          for (int fn = 0; fn < 4; fn++)
#pragma unroll
            for (int i = 0; i < 4; i++) {
              int pr = w * 16 + lg * 4 + i;
              int pg = (fn * 2 + (lr16 >> 3)) ^ (pr & 7);
              lP[pr * 64 + pg * 8 + (lr16 & 7)] = f2bf(accs[fn][i]);
            }
        }
      } else {
        // ---- PV unit nc: O += P * V ----
        const int nc = u - 8;
        if (u == 8) {
          int prow = w * 16 + lr16;
          pa0 = *reinterpret_cast<const bf16x8*>(&lP[prow * 64 + ((0 + lg) ^ (prow & 7)) * 8]);
          pa1 = *reinterpret_cast<const bf16x8*>(&lP[prow * 64 + ((4 + lg) ^ (prow & 7)) * 8]);
        }
#pragma unroll
        for (int fc = 0; fc < 8; fc++) {
          int row = fc * 16 + lr16;
          int p0i = (0 + lg) ^ (row & 7);
          int p1i = (4 + lg) ^ (row & 7);
          bf16x8 b0 = *reinterpret_cast<const bf16x8*>(&bp[row * 64 + p0i * 8]);
          bf16x8 b1 = *reinterpret_cast<const bf16x8*>(&bp[row * 64 + p1i * 8]);
          int f = nc * 8 + fc;
          acc_o[f] = __builtin_amdgcn_mfma_f32_16x16x32_bf16(pa0, b0, acc_o[f], 0, 0, 0);
          acc_o[f] = __builtin_amdgcn_mfma_f32_16x16x32_bf16(pa1, b1, acc_o[f], 0, 0, 0);
        }
      }
    }
  }

  // ---- epilogue: normalize and store fp32 ----
  float inv[4];
#pragma unroll
  for (int i = 0; i < 4; i++) inv[i] = 1.0f / l_s[i];
#pragma unroll
  for (int nc = 0; nc < 4; nc++)
#pragma unroll
    for (int fc = 0; fc < 8; fc++)
#pragma unroll
      for (int i = 0; i < 4; i++) {
        int row = q0 + w * 16 + lg * 4 + i;
        int col = nc * 128 + fc * 16 + lr16;
        Ob[(size_t)row * NO + col] = acc_o[nc * 8 + fc][i] * inv[i];
      }
}

extern "C" void kernel_launch(void* const* d_in, const int* in_sizes, int n_in,
                              void* d_out, int out_size, void* d_ws, size_t ws_size,
                              hipStream_t stream) {
  const float* x = (const float*)d_in[0];
  const float* Wq = (const float*)d_in[1];
  const float* bq = (const float*)d_in[2];
  const float* Wk = (const float*)d_in[3];
  const float* bk = (const float*)d_in[4];
  const float* Wv = (const float*)d_in[5];
  const float* bv = (const float*)d_in[6];
  float* out = (float*)d_out;
  char* ws = (char*)d_ws;

  // workspace layout (bytes)
  unsigned short* xb  = (unsigned short*)(ws + 0);          // 33,554,432
  unsigned short* wqt = (unsigned short*)(ws + 33554432);   //  2,097,152
  unsigned short* wkt = (unsigned short*)(ws + 35651584);   //  2,097,152
  unsigned short* wvt = (unsigned short*)(ws + 37748736);   //  1,048,576
  unsigned short* Qb  = (unsigned short*)(ws + 38797312);   // 33,554,432
  unsigned short* Kb  = (unsigned short*)(ws + 72351744);   // 33,554,432
  unsigned short* Vb  = (unsigned short*)(ws + 105906176);  // 16,777,216
  unsigned short* Vtb = (unsigned short*)(ws + 122683392);  // 16,777,216  (end ~133MB)

  // 1) casts
  cast_x_kernel<<<8192, 256, 0, stream>>>(x, xb, (NB * NS * ND) / 8);
  transpose_cast_kernel<<<dim3(32, 32), 256, 0, stream>>>(Wq, wqt, ND, ND);
  transpose_cast_kernel<<<dim3(32, 32), 256, 0, stream>>>(Wk, wkt, ND, ND);
  transpose_cast_kernel<<<dim3(16, 32), 256, 0, stream>>>(Wv, wvt, ND, NO);
  // 2) projections (M=16384)
  gemm_bias_kernel<<<dim3(128, 8), 256, 0, stream>>>(xb, wqt, bq, Qb, NB * NS, ND, ND);
  gemm_bias_kernel<<<dim3(128, 8), 256, 0, stream>>>(xb, wkt, bk, Kb, NB * NS, ND, ND);
  gemm_bias_kernel<<<dim3(128, 4), 256, 0, stream>>>(xb, wvt, bv, Vb, NB * NS, NO, ND);
  // 3) V transpose -> [B][O][S]
  transpose_v_kernel<<<dim3(16, 64, 8), 256, 0, stream>>>(Vb, Vtb);
  // 4) flash attention
  flash_kernel<<<256, 256, 0, stream>>>(Qb, Kb, Vtb, out);
}